// Round 2
// baseline (973.920 us; speedup 1.0000x reference)
//
#include <hip/hip_runtime.h>
#include <math.h>

#define S_LEN 1024
#define BATCH 2
#define DM 512
#define DI 1024
#define DS 128
#define DTR 32

// Generic tiled fp32 GEMM: C[M,N] = epi(A@B), A row-major [M,lda] (optionally + A2[M,lda2]),
// B row-major [K,N]. 64x64 tile, 256 threads, 4x4 per thread.
template<int EPI>
__global__ __launch_bounds__(256) void gemm_tiled(
    const float* __restrict__ A, int lda,
    const float* __restrict__ A2, int lda2,
    const float* __restrict__ B,
    const float* __restrict__ bias,
    float* __restrict__ C,
    int M, int N, int K) {
  __shared__ float As[16][65];
  __shared__ float Bs[16][65];
  const int bm = blockIdx.y * 64, bn = blockIdx.x * 64;
  const int tid = threadIdx.x;
  const int tx = tid & 15, ty = tid >> 4;
  float acc[4][4] = {};
  for (int k0 = 0; k0 < K; k0 += 16) {
    {
      const int kk = tid & 15;
      const int r0 = tid >> 4;
#pragma unroll
      for (int i = 0; i < 4; ++i) {
        int r = r0 + i * 16;
        int gm = bm + r, gk = k0 + kk;
        float v = 0.f;
        if (gm < M && gk < K) {
          v = A[(size_t)gm * lda + gk];
          if (A2) v += A2[(size_t)gm * lda2 + gk];
        }
        As[kk][r] = v;
      }
    }
    {
      const int n = tid & 63;
      const int kk0 = tid >> 6;
#pragma unroll
      for (int i = 0; i < 4; ++i) {
        int kk = kk0 + i * 4;
        int gk = k0 + kk, gn = bn + n;
        float v = 0.f;
        if (gk < K && gn < N) v = B[(size_t)gk * N + gn];
        Bs[kk][n] = v;
      }
    }
    __syncthreads();
#pragma unroll
    for (int kk = 0; kk < 16; ++kk) {
      float a[4], bb[4];
#pragma unroll
      for (int i = 0; i < 4; ++i) a[i] = As[kk][ty + 16 * i];
#pragma unroll
      for (int j = 0; j < 4; ++j) bb[j] = Bs[kk][tx + 16 * j];
#pragma unroll
      for (int i = 0; i < 4; ++i)
#pragma unroll
        for (int j = 0; j < 4; ++j)
          acc[i][j] = fmaf(a[i], bb[j], acc[i][j]);
    }
    __syncthreads();
  }
#pragma unroll
  for (int i = 0; i < 4; ++i) {
    int gm = bm + ty + 16 * i;
    if (gm >= M) continue;
#pragma unroll
    for (int j = 0; j < 4; ++j) {
      int gn = bn + tx + 16 * j;
      if (gn >= N) continue;
      float v = acc[i][j];
      if (EPI == 1) {
        v += bias[gn];
        v += 1e-4f;                              // DT_FLOOR
        v = (v > 20.f) ? v : log1pf(expf(v));    // softplus
        v = fminf(fmaxf(v, 0.001f), 0.1f);       // clip
      }
      C[(size_t)gm * N + gn] = v;
    }
  }
}

// Depthwise causal conv (kernel=4, left pad 3): u[b,s,d] = b[d] + sum_k xs[b,s-3+k,d]*w[d,k]
// xs[b,s,d] = xr[(b*S+s)*2048 + d] (first DI columns of the in-proj output)
__global__ __launch_bounds__(256) void conv_kernel(
    const float* __restrict__ xr, const float* __restrict__ w,
    const float* __restrict__ b, float* __restrict__ u) {
  int idx = blockIdx.x * blockDim.x + threadIdx.x;  // over B*S*DI = 2^21
  if (idx >= BATCH * S_LEN * DI) return;
  int d = idx & (DI - 1);
  int s = (idx >> 10) & (S_LEN - 1);
  int bb = idx >> 20;
  const float* xs = xr + (size_t)(bb * S_LEN) * (2 * DI) + d;
  float acc = b[d];
#pragma unroll
  for (int k = 0; k < 4; ++k) {
    int si = s - 3 + k;
    if (si >= 0) acc = fmaf(xs[(size_t)si * (2 * DI)], w[d * 4 + k], acc);
  }
  u[idx] = acc;
}

// Selective scan: one wave per (b,d). Lane holds h[2*lane], h[2*lane+1].
// dbl row layout: [0:32]=dt_in, [32:160]=B, [160:288]=C. Writes y over u in place.
__global__ __launch_bounds__(256) void scan_kernel(
    const float* __restrict__ dbl,
    const float* __restrict__ dtb,
    float* __restrict__ uy) {
  int wave = (blockIdx.x * blockDim.x + threadIdx.x) >> 6;  // 0..2047
  int lane = threadIdx.x & 63;
  int b = wave >> 10;
  int d = wave & (DI - 1);
  const float* dblb = dbl + (size_t)(b * S_LEN) * 288;
  const float* dtp = dtb + (size_t)(b * S_LEN) * DI + d;
  float* uyp = uy + (size_t)(b * S_LEN) * DI + d;
  float h0 = 0.f, h1 = 0.f;
  for (int s = 0; s < S_LEN; ++s) {
    float dt = dtp[(size_t)s * DI];
    float uv = uyp[(size_t)s * DI];
    const float* row = dblb + (size_t)s * 288;
    float2 Bv = *(const float2*)(row + 32 + 2 * lane);
    float2 Cv = *(const float2*)(row + 160 + 2 * lane);
    float om = 1.f - dt;
    h0 = fmaf(h0, om, uv * Bv.x);
    h1 = fmaf(h1, om, uv * Bv.y);
    float part = fmaf(h0, Cv.x, h1 * Cv.y);
#pragma unroll
    for (int off = 32; off; off >>= 1) part += __shfl_xor(part, off, 64);
    if (lane == 0) uyp[(size_t)s * DI] = part;
  }
}

extern "C" void kernel_launch(void* const* d_in, const int* in_sizes, int n_in,
                              void* d_out, int out_size, void* d_ws, size_t ws_size,
                              hipStream_t stream) {
  const float* x      = (const float*)d_in[0];
  const float* W_in   = (const float*)d_in[1];
  const float* conv_w = (const float*)d_in[2];
  const float* conv_b = (const float*)d_in[3];
  const float* W_x    = (const float*)d_in[4];
  const float* W_dt   = (const float*)d_in[5];
  const float* b_dt   = (const float*)d_in[6];
  const float* W_out  = (const float*)d_in[7];
  float* out = (float*)d_out;
  float* ws = (float*)d_ws;

  const int M = BATCH * S_LEN;      // 2048
  float* xr  = ws;                  // [2048, 2048]  (xs | res)
  float* u   = ws + 4194304;        // [2048, 1024]  (u, then y in-place)
  float* dbl = ws + 6291456;        // [2048, 288]
  float* dtb = ws + 6881280;        // [2048, 1024]

  dim3 blk(256);
  // 1) xr = x @ W_in            M=2048 N=2048 K=512
  gemm_tiled<0><<<dim3(32, 32), blk, 0, stream>>>(x, DM, nullptr, 0, W_in, nullptr, xr, M, 2 * DI, DM);
  // 2) depthwise causal conv -> u
  conv_kernel<<<(BATCH * S_LEN * DI) / 256, blk, 0, stream>>>(xr, conv_w, conv_b, u);
  // 3) dbl = u @ W_x            M=2048 N=288 K=1024
  gemm_tiled<0><<<dim3(5, 32), blk, 0, stream>>>(u, DI, nullptr, 0, W_x, nullptr, dbl, M, DTR + 2 * DS, DI);
  // 4) dt = softplus-clip(dbl[:, :32] @ W_dt + b_dt)   M=2048 N=1024 K=32
  gemm_tiled<1><<<dim3(16, 32), blk, 0, stream>>>(dbl, 288, nullptr, 0, W_dt, b_dt, dtb, M, DI, DTR);
  // 5) selective scan, y over u in place
  scan_kernel<<<(BATCH * DI * 64) / 256, blk, 0, stream>>>(dbl, dtb, u);
  // 6) out = (y + res) @ W_out  M=2048 N=512 K=1024 ; res = xr[:, 1024:]
  gemm_tiled<0><<<dim3(8, 32), blk, 0, stream>>>(u, DI, xr + DI, 2 * DI, W_out, nullptr, out, M, DM, DI);
}

// Round 3
// 737.475 us; speedup vs baseline: 1.3206x; 1.3206x over previous
//
#include <hip/hip_runtime.h>
#include <math.h>

#define S_LEN 1024
#define BATCH 2
#define DM 512
#define DI 1024
#define DS 128
#define DTR 32
#define CL 64            // chunk length
#define NC (S_LEN / CL)  // 16 chunks

// Generic tiled fp32 GEMM: C[M,N] = epi(A@B), A row-major [M,lda] (optionally + A2[M,lda2]),
// B row-major [K,N]. 64x64 tile, 256 threads, 4x4 per thread.
template<int EPI>
__global__ __launch_bounds__(256) void gemm_tiled(
    const float* __restrict__ A, int lda,
    const float* __restrict__ A2, int lda2,
    const float* __restrict__ B,
    const float* __restrict__ bias,
    float* __restrict__ C,
    int M, int N, int K) {
  __shared__ float As[16][65];
  __shared__ float Bs[16][65];
  const int bm = blockIdx.y * 64, bn = blockIdx.x * 64;
  const int tid = threadIdx.x;
  const int tx = tid & 15, ty = tid >> 4;
  float acc[4][4] = {};
  for (int k0 = 0; k0 < K; k0 += 16) {
    {
      const int kk = tid & 15;
      const int r0 = tid >> 4;
#pragma unroll
      for (int i = 0; i < 4; ++i) {
        int r = r0 + i * 16;
        int gm = bm + r, gk = k0 + kk;
        float v = 0.f;
        if (gm < M && gk < K) {
          v = A[(size_t)gm * lda + gk];
          if (A2) v += A2[(size_t)gm * lda2 + gk];
        }
        As[kk][r] = v;
      }
    }
    {
      const int n = tid & 63;
      const int kk0 = tid >> 6;
#pragma unroll
      for (int i = 0; i < 4; ++i) {
        int kk = kk0 + i * 4;
        int gk = k0 + kk, gn = bn + n;
        float v = 0.f;
        if (gk < K && gn < N) v = B[(size_t)gk * N + gn];
        Bs[kk][n] = v;
      }
    }
    __syncthreads();
#pragma unroll
    for (int kk = 0; kk < 16; ++kk) {
      float a[4], bb[4];
#pragma unroll
      for (int i = 0; i < 4; ++i) a[i] = As[kk][ty + 16 * i];
#pragma unroll
      for (int j = 0; j < 4; ++j) bb[j] = Bs[kk][tx + 16 * j];
#pragma unroll
      for (int i = 0; i < 4; ++i)
#pragma unroll
        for (int j = 0; j < 4; ++j)
          acc[i][j] = fmaf(a[i], bb[j], acc[i][j]);
    }
    __syncthreads();
  }
#pragma unroll
  for (int i = 0; i < 4; ++i) {
    int gm = bm + ty + 16 * i;
    if (gm >= M) continue;
#pragma unroll
    for (int j = 0; j < 4; ++j) {
      int gn = bn + tx + 16 * j;
      if (gn >= N) continue;
      float v = acc[i][j];
      if (EPI == 1) {
        v += bias[gn];
        v += 1e-4f;                              // DT_FLOOR
        v = (v > 20.f) ? v : log1pf(expf(v));    // softplus
        v = fminf(fmaxf(v, 0.001f), 0.1f);       // clip
      }
      C[(size_t)gm * N + gn] = v;
    }
  }
}

// Depthwise causal conv (kernel=4, left pad 3): u[b,s,d] = b[d] + sum_k xs[b,s-3+k,d]*w[d,k]
__global__ __launch_bounds__(256) void conv_kernel(
    const float* __restrict__ xr, const float* __restrict__ w,
    const float* __restrict__ b, float* __restrict__ u) {
  int idx = blockIdx.x * blockDim.x + threadIdx.x;  // over B*S*DI = 2^21
  if (idx >= BATCH * S_LEN * DI) return;
  int d = idx & (DI - 1);
  int s = (idx >> 10) & (S_LEN - 1);
  int bb = idx >> 20;
  const float* xs = xr + (size_t)(bb * S_LEN) * (2 * DI) + d;
  float acc = b[d];
#pragma unroll
  for (int k = 0; k < 4; ++k) {
    int si = s - 3 + k;
    if (si >= 0) acc = fmaf(xs[(size_t)si * (2 * DI)], w[d * 4 + k], acc);
  }
  u[idx] = acc;
}

// ---- Chunked selective scan --------------------------------------------------
// Recurrence h_t = (1-dt_t) h_{t-1} + u_t B_t is linear in h. Per chunk of CL
// steps: pass1 computes the chunk-local end state (h_in=0) and decay product;
// pass2 sequentially combines 16 chunk boundaries; pass3 rescans each chunk
// from its true entry state and emits y. Serial depth 1024 -> 64+16+64.
// dbl row layout: [0:32]=dt_in, [32:160]=B, [160:288]=C.
// hst layout: [(b*DI+d)*NC + c]*128 + 2*lane (pass1 writes hz_end; pass2
// overwrites with chunk-entry state H[c]).

__global__ __launch_bounds__(256) void scan_pass1(
    const float* __restrict__ dbl, const float* __restrict__ dtb,
    const float* __restrict__ u, float* __restrict__ hst,
    float* __restrict__ Aarr) {
  int wid = (blockIdx.x * blockDim.x + threadIdx.x) >> 6;  // 0..32767
  int lane = threadIdx.x & 63;
  int d = wid & (DI - 1);
  int c = (wid >> 10) & (NC - 1);
  int b = wid >> 14;
  int s0 = c * CL;
  const float* dtp = dtb + ((size_t)(b * S_LEN + s0)) * DI + d;
  const float* up  = u   + ((size_t)(b * S_LEN + s0)) * DI + d;
  const float* Bp  = dbl + ((size_t)(b * S_LEN + s0)) * 288 + 32 + 2 * lane;
  float h0 = 0.f, h1 = 0.f, A = 1.f;
  for (int i = 0; i < CL; ++i) {
    float dt = dtp[(size_t)i * DI];
    float uv = up[(size_t)i * DI];
    float2 Bv = *(const float2*)(Bp + (size_t)i * 288);
    float om = 1.f - dt;
    A *= om;
    h0 = fmaf(h0, om, uv * Bv.x);
    h1 = fmaf(h1, om, uv * Bv.y);
  }
  size_t hbase = (((size_t)(b * DI + d)) * NC + c) * 128;
  *(float2*)(hst + hbase + 2 * lane) = make_float2(h0, h1);
  if (lane == 0) Aarr[(size_t)(b * DI + d) * NC + c] = A;
}

__global__ __launch_bounds__(256) void scan_pass2(
    float* __restrict__ hst, const float* __restrict__ Aarr) {
  int wid = (blockIdx.x * blockDim.x + threadIdx.x) >> 6;  // 0..2047 = b*DI+d
  int lane = threadIdx.x & 63;
  size_t base = (size_t)wid * NC * 128;
  float hin0 = 0.f, hin1 = 0.f;
  for (int c = 0; c < NC; ++c) {
    float2 he = *(const float2*)(hst + base + c * 128 + 2 * lane);
    float A = Aarr[(size_t)wid * NC + c];
    *(float2*)(hst + base + c * 128 + 2 * lane) = make_float2(hin0, hin1);
    hin0 = fmaf(A, hin0, he.x);
    hin1 = fmaf(A, hin1, he.y);
  }
}

__global__ __launch_bounds__(256) void scan_pass3(
    const float* __restrict__ dbl, const float* __restrict__ dtb,
    const float* __restrict__ u, const float* __restrict__ hst,
    float* __restrict__ y) {
  int wid = (blockIdx.x * blockDim.x + threadIdx.x) >> 6;  // 0..32767
  int lane = threadIdx.x & 63;
  int d = wid & (DI - 1);
  int c = (wid >> 10) & (NC - 1);
  int b = wid >> 14;
  int s0 = c * CL;
  const float* dtp  = dtb + ((size_t)(b * S_LEN + s0)) * DI + d;
  const float* up   = u   + ((size_t)(b * S_LEN + s0)) * DI + d;
  const float* rowp = dbl + ((size_t)(b * S_LEN + s0)) * 288;
  float* yp = y + ((size_t)(b * S_LEN + s0)) * DI + d;
  size_t hbase = (((size_t)(b * DI + d)) * NC + c) * 128;
  float2 h = *(const float2*)(hst + hbase + 2 * lane);
  float h0 = h.x, h1 = h.y;
  for (int i = 0; i < CL; ++i) {
    float dt = dtp[(size_t)i * DI];
    float uv = up[(size_t)i * DI];
    const float* row = rowp + (size_t)i * 288;
    float2 Bv = *(const float2*)(row + 32 + 2 * lane);
    float2 Cv = *(const float2*)(row + 160 + 2 * lane);
    float om = 1.f - dt;
    h0 = fmaf(h0, om, uv * Bv.x);
    h1 = fmaf(h1, om, uv * Bv.y);
    float part = fmaf(h0, Cv.x, h1 * Cv.y);
#pragma unroll
    for (int off = 32; off; off >>= 1) part += __shfl_xor(part, off, 64);
    if (lane == 0) yp[(size_t)i * DI] = part;
  }
}

extern "C" void kernel_launch(void* const* d_in, const int* in_sizes, int n_in,
                              void* d_out, int out_size, void* d_ws, size_t ws_size,
                              hipStream_t stream) {
  const float* x      = (const float*)d_in[0];
  const float* W_in   = (const float*)d_in[1];
  const float* conv_w = (const float*)d_in[2];
  const float* conv_b = (const float*)d_in[3];
  const float* W_x    = (const float*)d_in[4];
  const float* W_dt   = (const float*)d_in[5];
  const float* b_dt   = (const float*)d_in[6];
  const float* W_out  = (const float*)d_in[7];
  float* out = (float*)d_out;
  float* ws = (float*)d_ws;

  const int M = BATCH * S_LEN;       // 2048
  float* xr  = ws;                   // [2048, 2048] = 16 MB  (xs | res)
  float* u   = ws + 4194304;         // [2048, 1024] = 8 MB
  float* dbl = ws + 6291456;         // [2048, 288]  = 2.25 MB
  float* dtb = ws + 6881280;         // [2048, 1024] = 8 MB
  float* y   = ws + 8978432;         // [2048, 1024] = 8 MB
  float* hst = ws + 11075584;        // [2,1024,16,128] = 16 MB
  float* Aar = ws + 15269888;        // [2,1024,16]  = 128 KB

  dim3 blk(256);
  // 1) xr = x @ W_in            M=2048 N=2048 K=512
  gemm_tiled<0><<<dim3(32, 32), blk, 0, stream>>>(x, DM, nullptr, 0, W_in, nullptr, xr, M, 2 * DI, DM);
  // 2) depthwise causal conv -> u
  conv_kernel<<<(BATCH * S_LEN * DI) / 256, blk, 0, stream>>>(xr, conv_w, conv_b, u);
  // 3) dbl = u @ W_x            M=2048 N=288 K=1024
  gemm_tiled<0><<<dim3(5, 32), blk, 0, stream>>>(u, DI, nullptr, 0, W_x, nullptr, dbl, M, DTR + 2 * DS, DI);
  // 4) dt = softplus-clip(dbl[:, :32] @ W_dt + b_dt)   M=2048 N=1024 K=32
  gemm_tiled<1><<<dim3(16, 32), blk, 0, stream>>>(dbl, 288, nullptr, 0, W_dt, b_dt, dtb, M, DI, DTR);
  // 5) chunked selective scan -> y
  scan_pass1<<<(BATCH * DI * NC * 64) / 256, blk, 0, stream>>>(dbl, dtb, u, hst, Aar);
  scan_pass2<<<(BATCH * DI * 64) / 256, blk, 0, stream>>>(hst, Aar);
  scan_pass3<<<(BATCH * DI * NC * 64) / 256, blk, 0, stream>>>(dbl, dtb, u, hst, y);
  // 6) out = (y + res) @ W_out  M=2048 N=512 K=1024 ; res = xr[:, 1024:]
  gemm_tiled<0><<<dim3(8, 32), blk, 0, stream>>>(y, DI, xr + DI, 2 * DI, W_out, nullptr, out, M, DM, DI);
}

// Round 4
// 377.985 us; speedup vs baseline: 2.5766x; 1.9511x over previous
//
#include <hip/hip_runtime.h>
#include <math.h>

#define S_LEN 1024
#define BATCH 2
#define DM 512
#define DI 1024
#define DS 128
#define DTR 32
#define CL 64            // chunk length
#define NC (S_LEN / CL)  // 16 chunks

typedef unsigned short ushortT;
typedef __attribute__((ext_vector_type(8))) short short8;
typedef __attribute__((ext_vector_type(4))) float f32x4;

__device__ __forceinline__ ushortT f2b(float f) {
  unsigned u = __builtin_bit_cast(unsigned, f);
  unsigned r = (u + 0x7fff + ((u >> 16) & 1)) >> 16;  // RNE
  return (ushortT)r;
}
__device__ __forceinline__ float b2f(ushortT h) {
  return __builtin_bit_cast(float, (unsigned)h << 16);
}

#define GLOAD16(g, l)                                                     \
  __builtin_amdgcn_global_load_lds(                                       \
      (const __attribute__((address_space(1))) void*)(g),                 \
      (__attribute__((address_space(3))) void*)(l), 16, 0, 0)

// ---- bf16 MFMA GEMM: C[M,N] = A[M,K] @ Bt[Npad,K]^T -------------------------
// 128x128 tile, 256 threads = 4 waves (2x2), each wave 64x64 = 4x4 frags of
// 16x16x32 MFMA. A,Bt row-major bf16 with contiguous K. OUTBF: C as bf16.
template<int OUTBF>
__global__ __launch_bounds__(256) void gemm_mfma(
    const ushortT* __restrict__ A, const ushortT* __restrict__ Bt,
    void* __restrict__ Cout, int N, int K, int ldc) {
  __shared__ ushortT As[128 * 32];
  __shared__ ushortT Bs[128 * 32];
  const int tid = threadIdx.x;
  const int l = tid & 63, w = tid >> 6;
  const int wr = w >> 1, wc = w & 1;
  const int bm = blockIdx.y * 128, bn = blockIdx.x * 128;
  const int srow = l >> 2, scol = (l & 3) * 8;  // staging: 4 lanes/row
  f32x4 acc[4][4] = {};
  for (int k0 = 0; k0 < K; k0 += 32) {
    // stage A,Bt tiles (each wave: 2 A-issues + 2 B-issues of 1KB)
#pragma unroll
    for (int j = 0; j < 2; ++j) {
      int sub = w * 2 + j;
      const ushortT* gA = A + (size_t)(bm + sub * 16 + srow) * K + k0 + scol;
      GLOAD16(gA, &As[sub * 512]);
      const ushortT* gB = Bt + (size_t)(bn + sub * 16 + srow) * K + k0 + scol;
      GLOAD16(gB, &Bs[sub * 512]);
    }
    __syncthreads();
    short8 a[4], b[4];
#pragma unroll
    for (int m = 0; m < 4; ++m)
      a[m] = *(const short8*)&As[(wr * 64 + m * 16 + (l & 15)) * 32 + (l >> 4) * 8];
#pragma unroll
    for (int n = 0; n < 4; ++n)
      b[n] = *(const short8*)&Bs[(wc * 64 + n * 16 + (l & 15)) * 32 + (l >> 4) * 8];
#pragma unroll
    for (int m = 0; m < 4; ++m)
#pragma unroll
      for (int n = 0; n < 4; ++n)
        acc[m][n] = __builtin_amdgcn_mfma_f32_16x16x32_bf16(a[m], b[n], acc[m][n], 0, 0, 0);
    __syncthreads();
  }
  // C/D layout (m89): col = l&15, row = (l>>4)*4 + i
#pragma unroll
  for (int m = 0; m < 4; ++m) {
    int grow = bm + wr * 64 + m * 16 + (l >> 4) * 4;
#pragma unroll
    for (int n = 0; n < 4; ++n) {
      int gcol = bn + wc * 64 + n * 16 + (l & 15);
      if (gcol >= N) continue;
#pragma unroll
      for (int i = 0; i < 4; ++i) {
        if (OUTBF)
          ((ushortT*)Cout)[(size_t)(grow + i) * ldc + gcol] = f2b(acc[m][n][i]);
        else
          ((float*)Cout)[(size_t)(grow + i) * ldc + gcol] = acc[m][n][i];
      }
    }
  }
}

// ---- fp32 tiled GEMM (kept for dt-proj, K=32) -------------------------------
template<int EPI>
__global__ __launch_bounds__(256) void gemm_tiled(
    const float* __restrict__ A, int lda,
    const float* __restrict__ B,
    const float* __restrict__ bias,
    float* __restrict__ C,
    int M, int N, int K) {
  __shared__ float As[16][65];
  __shared__ float Bs[16][65];
  const int bm = blockIdx.y * 64, bn = blockIdx.x * 64;
  const int tid = threadIdx.x;
  const int tx = tid & 15, ty = tid >> 4;
  float acc[4][4] = {};
  for (int k0 = 0; k0 < K; k0 += 16) {
    {
      const int kk = tid & 15;
      const int r0 = tid >> 4;
#pragma unroll
      for (int i = 0; i < 4; ++i) {
        int r = r0 + i * 16;
        int gm = bm + r, gk = k0 + kk;
        float v = 0.f;
        if (gm < M && gk < K) v = A[(size_t)gm * lda + gk];
        As[kk][r] = v;
      }
    }
    {
      const int n = tid & 63;
      const int kk0 = tid >> 6;
#pragma unroll
      for (int i = 0; i < 4; ++i) {
        int kk = kk0 + i * 4;
        int gk = k0 + kk, gn = bn + n;
        float v = 0.f;
        if (gk < K && gn < N) v = B[(size_t)gk * N + gn];
        Bs[kk][n] = v;
      }
    }
    __syncthreads();
#pragma unroll
    for (int kk = 0; kk < 16; ++kk) {
      float a[4], bb[4];
#pragma unroll
      for (int i = 0; i < 4; ++i) a[i] = As[kk][ty + 16 * i];
#pragma unroll
      for (int j = 0; j < 4; ++j) bb[j] = Bs[kk][tx + 16 * j];
#pragma unroll
      for (int i = 0; i < 4; ++i)
#pragma unroll
        for (int j = 0; j < 4; ++j)
          acc[i][j] = fmaf(a[i], bb[j], acc[i][j]);
    }
    __syncthreads();
  }
#pragma unroll
  for (int i = 0; i < 4; ++i) {
    int gm = bm + ty + 16 * i;
    if (gm >= M) continue;
#pragma unroll
    for (int j = 0; j < 4; ++j) {
      int gn = bn + tx + 16 * j;
      if (gn >= N) continue;
      float v = acc[i][j];
      if (EPI == 1) {
        v += bias[gn];
        v += 1e-4f;                              // DT_FLOOR
        v = (v > 20.f) ? v : log1pf(expf(v));    // softplus
        v = fminf(fmaxf(v, 0.001f), 0.1f);       // clip
      }
      C[(size_t)gm * N + gn] = v;
    }
  }
}

// ---- transpose + fp32->bf16: in[K,N] -> out[Npad,K], zero-pad rows >= N ----
__global__ __launch_bounds__(256) void transpose_cvt(
    const float* __restrict__ in, ushortT* __restrict__ out,
    int K, int N) {
  __shared__ float t[32][33];
  int n0 = blockIdx.x * 32, k0 = blockIdx.y * 32;
  int tx = threadIdx.x, ty = threadIdx.y;  // block (32,8)
  if (n0 < N) {  // N is a multiple of 32 -> tile fully valid
#pragma unroll
    for (int i = 0; i < 4; ++i)
      t[ty + 8 * i][tx] = in[(size_t)(k0 + ty + 8 * i) * N + n0 + tx];
    __syncthreads();
#pragma unroll
    for (int i = 0; i < 4; ++i)
      out[(size_t)(n0 + ty + 8 * i) * K + k0 + tx] = f2b(t[tx][ty + 8 * i]);
  } else {
#pragma unroll
    for (int i = 0; i < 4; ++i)
      out[(size_t)(n0 + ty + 8 * i) * K + k0 + tx] = 0;
  }
}

// ---- fp32 -> bf16 elementwise (4/thread) -----------------------------------
__global__ __launch_bounds__(256) void cvt_bf16(
    const float* __restrict__ in, ushortT* __restrict__ out) {
  int i = blockIdx.x * blockDim.x + threadIdx.x;
  float4 v = ((const float4*)in)[i];
  ushort4 o;
  o.x = f2b(v.x); o.y = f2b(v.y); o.z = f2b(v.z); o.w = f2b(v.w);
  ((ushort4*)out)[i] = o;
}

// ---- yr = bf16(y + res); res = xr_bf[:, 1024:2048] -------------------------
__global__ __launch_bounds__(256) void addcvt_yr(
    const float* __restrict__ y, const ushortT* __restrict__ xr_bf,
    ushortT* __restrict__ yr) {
  int i = blockIdx.x * blockDim.x + threadIdx.x;  // per 4 elems of [2048,1024]
  int row = i >> 8, col = (i & 255) * 4;
  float4 yv = ((const float4*)y)[i];
  ushort4 rv = *(const ushort4*)&xr_bf[(size_t)row * 2048 + 1024 + col];
  ushort4 o;
  o.x = f2b(yv.x + b2f(rv.x));
  o.y = f2b(yv.y + b2f(rv.y));
  o.z = f2b(yv.z + b2f(rv.z));
  o.w = f2b(yv.w + b2f(rv.w));
  ((ushort4*)yr)[i] = o;
}

// ---- depthwise causal conv (bf16 in, bf16 out) -----------------------------
__global__ __launch_bounds__(256) void conv_kernel(
    const ushortT* __restrict__ xr, const float* __restrict__ w,
    const float* __restrict__ b, ushortT* __restrict__ u) {
  int idx = blockIdx.x * blockDim.x + threadIdx.x;  // over B*S*DI
  int d = idx & (DI - 1);
  int s = (idx >> 10) & (S_LEN - 1);
  int bb = idx >> 20;
  const ushortT* xs = xr + (size_t)(bb * S_LEN) * (2 * DI) + d;
  float acc = b[d];
#pragma unroll
  for (int k = 0; k < 4; ++k) {
    int si = s - 3 + k;
    if (si >= 0) acc = fmaf(b2f(xs[(size_t)si * (2 * DI)]), w[d * 4 + k], acc);
  }
  u[idx] = f2b(acc);
}

// ---- chunked selective scan -------------------------------------------------
__global__ __launch_bounds__(256) void scan_pass1(
    const float* __restrict__ dbl, const float* __restrict__ dtb,
    const ushortT* __restrict__ u, float* __restrict__ hst,
    float* __restrict__ Aarr) {
  int wid = (blockIdx.x * blockDim.x + threadIdx.x) >> 6;  // 0..32767
  int lane = threadIdx.x & 63;
  int d = wid & (DI - 1);
  int c = (wid >> 10) & (NC - 1);
  int b = wid >> 14;
  int s0 = c * CL;
  const float* dtp = dtb + ((size_t)(b * S_LEN + s0)) * DI + d;
  const ushortT* up = u + ((size_t)(b * S_LEN + s0)) * DI + d;
  const float* Bp = dbl + ((size_t)(b * S_LEN + s0)) * 288 + 32 + 2 * lane;
  float h0 = 0.f, h1 = 0.f, A = 1.f;
  for (int i = 0; i < CL; ++i) {
    float dt = dtp[(size_t)i * DI];
    float uv = b2f(up[(size_t)i * DI]);
    float2 Bv = *(const float2*)(Bp + (size_t)i * 288);
    float om = 1.f - dt;
    A *= om;
    h0 = fmaf(h0, om, uv * Bv.x);
    h1 = fmaf(h1, om, uv * Bv.y);
  }
  size_t hbase = (((size_t)(b * DI + d)) * NC + c) * 128;
  *(float2*)(hst + hbase + 2 * lane) = make_float2(h0, h1);
  if (lane == 0) Aarr[(size_t)(b * DI + d) * NC + c] = A;
}

__global__ __launch_bounds__(256) void scan_pass2(
    float* __restrict__ hst, const float* __restrict__ Aarr) {
  int wid = (blockIdx.x * blockDim.x + threadIdx.x) >> 6;  // 0..2047
  int lane = threadIdx.x & 63;
  size_t base = (size_t)wid * NC * 128;
  float hin0 = 0.f, hin1 = 0.f;
  for (int c = 0; c < NC; ++c) {
    float2 he = *(const float2*)(hst + base + c * 128 + 2 * lane);
    float A = Aarr[(size_t)wid * NC + c];
    *(float2*)(hst + base + c * 128 + 2 * lane) = make_float2(hin0, hin1);
    hin0 = fmaf(A, hin0, he.x);
    hin1 = fmaf(A, hin1, he.y);
  }
}

__global__ __launch_bounds__(256) void scan_pass3(
    const float* __restrict__ dbl, const float* __restrict__ dtb,
    const ushortT* __restrict__ u, const float* __restrict__ hst,
    float* __restrict__ y) {
  int wid = (blockIdx.x * blockDim.x + threadIdx.x) >> 6;  // 0..32767
  int lane = threadIdx.x & 63;
  int d = wid & (DI - 1);
  int c = (wid >> 10) & (NC - 1);
  int b = wid >> 14;
  int s0 = c * CL;
  const float* dtp = dtb + ((size_t)(b * S_LEN + s0)) * DI + d;
  const ushortT* up = u + ((size_t)(b * S_LEN + s0)) * DI + d;
  const float* rowp = dbl + ((size_t)(b * S_LEN + s0)) * 288;
  float* yp = y + ((size_t)(b * S_LEN + s0)) * DI + d;
  size_t hbase = (((size_t)(b * DI + d)) * NC + c) * 128;
  float2 h = *(const float2*)(hst + hbase + 2 * lane);
  float h0 = h.x, h1 = h.y;
  for (int i = 0; i < CL; ++i) {
    float dt = dtp[(size_t)i * DI];
    float uv = b2f(up[(size_t)i * DI]);
    const float* row = rowp + (size_t)i * 288;
    float2 Bv = *(const float2*)(row + 32 + 2 * lane);
    float2 Cv = *(const float2*)(row + 160 + 2 * lane);
    float om = 1.f - dt;
    h0 = fmaf(h0, om, uv * Bv.x);
    h1 = fmaf(h1, om, uv * Bv.y);
    float part = fmaf(h0, Cv.x, h1 * Cv.y);
#pragma unroll
    for (int off = 32; off; off >>= 1) part += __shfl_xor(part, off, 64);
    if (lane == 0) yp[(size_t)i * DI] = part;
  }
}

extern "C" void kernel_launch(void* const* d_in, const int* in_sizes, int n_in,
                              void* d_out, int out_size, void* d_ws, size_t ws_size,
                              hipStream_t stream) {
  const float* x      = (const float*)d_in[0];
  const float* W_in   = (const float*)d_in[1];
  const float* conv_w = (const float*)d_in[2];
  const float* conv_b = (const float*)d_in[3];
  const float* W_x    = (const float*)d_in[4];
  const float* W_dt   = (const float*)d_in[5];
  const float* b_dt   = (const float*)d_in[6];
  const float* W_out  = (const float*)d_in[7];
  float* out = (float*)d_out;
  float* ws = (float*)d_ws;

  const int M = BATCH * S_LEN;  // 2048
  // workspace layout (float-unit offsets; total 14,712,832 floats = 58.9 MB)
  ushortT* xr_bf  = (ushortT*)ws;                    // [2048,2048] bf16
  ushortT* u_bf   = (ushortT*)(ws + 2097152);        // [2048,1024] bf16
  float*   dbl    = ws + 3145728;                    // [2048,288]
  float*   dtb    = ws + 3735552;                    // [2048,1024]
  float*   y      = ws + 5832704;                    // [2048,1024]
  float*   hst    = ws + 7929856;                    // [2,1024,16,128]
  float*   Aar    = ws + 12124160;                   // [2,1024,16]
  ushortT* x_bf   = (ushortT*)(ws + 12156928);       // [2048,512] bf16
  ushortT* Wt_in  = (ushortT*)(ws + 12681216);       // [2048,512] bf16
  ushortT* Wt_x   = (ushortT*)(ws + 13205504);       // [384,1024] bf16 (padded)
  ushortT* Wt_out = (ushortT*)(ws + 13402112);       // [512,1024] bf16
  ushortT* yr_bf  = (ushortT*)(ws + 13664256);       // [2048,1024] bf16

  dim3 blk(256);
  dim3 tblk(32, 8);
  // weight transposes + x conversion
  transpose_cvt<<<dim3(64, 16), tblk, 0, stream>>>(W_in, Wt_in, DM, 2 * DI);
  transpose_cvt<<<dim3(12, 32), tblk, 0, stream>>>(W_x, Wt_x, DI, DTR + 2 * DS);
  transpose_cvt<<<dim3(16, 32), tblk, 0, stream>>>(W_out, Wt_out, DI, DM);
  cvt_bf16<<<1024, blk, 0, stream>>>(x, x_bf);
  // 1) xr = x @ W_in  (bf16 out)      M=2048 N=2048 K=512
  gemm_mfma<1><<<dim3(16, 16), blk, 0, stream>>>(x_bf, Wt_in, xr_bf, 2 * DI, DM, 2 * DI);
  // 2) depthwise causal conv -> u (bf16)
  conv_kernel<<<(BATCH * S_LEN * DI) / 256, blk, 0, stream>>>(xr_bf, conv_w, conv_b, u_bf);
  // 3) dbl = u @ W_x  (fp32 out)      M=2048 N=288 K=1024 (Bt padded to 384)
  gemm_mfma<0><<<dim3(3, 16), blk, 0, stream>>>(u_bf, Wt_x, dbl, DTR + 2 * DS, DI, DTR + 2 * DS);
  // 4) dt = softplus-clip(dbl[:, :32] @ W_dt + b_dt)   M=2048 N=1024 K=32
  gemm_tiled<1><<<dim3(16, 32), blk, 0, stream>>>(dbl, 288, W_dt, b_dt, dtb, M, DI, DTR);
  // 5) chunked selective scan -> y (fp32)
  scan_pass1<<<(BATCH * DI * NC * 64) / 256, blk, 0, stream>>>(dbl, dtb, u_bf, hst, Aar);
  scan_pass2<<<(BATCH * DI * 64) / 256, blk, 0, stream>>>(hst, Aar);
  scan_pass3<<<(BATCH * DI * NC * 64) / 256, blk, 0, stream>>>(dbl, dtb, u_bf, hst, y);
  // 6) yr = bf16(y + res); out = yr @ W_out   M=2048 N=512 K=1024
  addcvt_yr<<<2048, blk, 0, stream>>>(y, xr_bf, yr_bf);
  gemm_mfma<0><<<dim3(4, 16), blk, 0, stream>>>(yr_bf, Wt_out, out, DM, DI, DM);
}

// Round 6
// 181.245 us; speedup vs baseline: 5.3735x; 2.0855x over previous
//
#include <hip/hip_runtime.h>
#include <math.h>

#define S_LEN 1024
#define BATCH 2
#define DM 512
#define DI 1024
#define DS 128
#define DTR 32
#define CL 64            // chunk length
#define NC (S_LEN / CL)  // 16 chunks

typedef unsigned short ushortT;
typedef __attribute__((ext_vector_type(8))) short short8;
typedef __attribute__((ext_vector_type(4))) float f32x4;

__device__ __forceinline__ ushortT f2b(float f) {
  unsigned u = __builtin_bit_cast(unsigned, f);
  unsigned r = (u + 0x7fff + ((u >> 16) & 1)) >> 16;  // RNE
  return (ushortT)r;
}
__device__ __forceinline__ float b2f(ushortT h) {
  return __builtin_bit_cast(float, (unsigned)h << 16);
}

#define GLOAD16(g, l)                                                     \
  __builtin_amdgcn_global_load_lds(                                       \
      (const __attribute__((address_space(1))) void*)(g),                 \
      (__attribute__((address_space(3))) void*)(l), 16, 0, 0)

// ---- bf16 MFMA GEMM: C[M,N] = A[M,K] @ Bt[Npad,K]^T -------------------------
// 128x128 tile, 256 threads = 4 waves (2x2). MODE 0: fp32 out; 1: bf16 out;
// 2: fp32 out with bias + DT_FLOOR + softplus + clip (dt-proj epilogue).
template<int MODE>
__global__ __launch_bounds__(256) void gemm_mfma(
    const ushortT* __restrict__ A, const ushortT* __restrict__ Bt,
    const float* __restrict__ bias,
    void* __restrict__ Cout, int N, int K, int ldc) {
  __shared__ ushortT As[128 * 32];
  __shared__ ushortT Bs[128 * 32];
  const int tid = threadIdx.x;
  const int l = tid & 63, w = tid >> 6;
  const int wr = w >> 1, wc = w & 1;
  const int bm = blockIdx.y * 128, bn = blockIdx.x * 128;
  const int srow = l >> 2, scol = (l & 3) * 8;
  f32x4 acc[4][4] = {};
  for (int k0 = 0; k0 < K; k0 += 32) {
#pragma unroll
    for (int j = 0; j < 2; ++j) {
      int sub = w * 2 + j;
      const ushortT* gA = A + (size_t)(bm + sub * 16 + srow) * K + k0 + scol;
      GLOAD16(gA, &As[sub * 512]);
      const ushortT* gB = Bt + (size_t)(bn + sub * 16 + srow) * K + k0 + scol;
      GLOAD16(gB, &Bs[sub * 512]);
    }
    __syncthreads();
    short8 a[4], b[4];
#pragma unroll
    for (int m = 0; m < 4; ++m)
      a[m] = *(const short8*)&As[(wr * 64 + m * 16 + (l & 15)) * 32 + (l >> 4) * 8];
#pragma unroll
    for (int n = 0; n < 4; ++n)
      b[n] = *(const short8*)&Bs[(wc * 64 + n * 16 + (l & 15)) * 32 + (l >> 4) * 8];
#pragma unroll
    for (int m = 0; m < 4; ++m)
#pragma unroll
      for (int n = 0; n < 4; ++n)
        acc[m][n] = __builtin_amdgcn_mfma_f32_16x16x32_bf16(a[m], b[n], acc[m][n], 0, 0, 0);
    __syncthreads();
  }
#pragma unroll
  for (int m = 0; m < 4; ++m) {
    int grow = bm + wr * 64 + m * 16 + (l >> 4) * 4;
#pragma unroll
    for (int n = 0; n < 4; ++n) {
      int gcol = bn + wc * 64 + n * 16 + (l & 15);
      if (gcol >= N) continue;
#pragma unroll
      for (int i = 0; i < 4; ++i) {
        float v = acc[m][n][i];
        if (MODE == 1)
          ((ushortT*)Cout)[(size_t)(grow + i) * ldc + gcol] = f2b(v);
        else if (MODE == 2) {
          v += bias[gcol] + 1e-4f;
          v = (v > 20.f) ? v : log1pf(expf(v));
          v = fminf(fmaxf(v, 0.001f), 0.1f);
          ((float*)Cout)[(size_t)(grow + i) * ldc + gcol] = v;
        } else
          ((float*)Cout)[(size_t)(grow + i) * ldc + gcol] = v;
      }
    }
  }
}

// ---- transpose + fp32->bf16: in[K,N] -> out[Npad,K], zero-pad rows >= N ----
__global__ __launch_bounds__(256) void transpose_cvt(
    const float* __restrict__ in, ushortT* __restrict__ out, int K, int N) {
  __shared__ float t[32][33];
  int n0 = blockIdx.x * 32, k0 = blockIdx.y * 32;
  int tx = threadIdx.x, ty = threadIdx.y;  // block (32,8)
  if (n0 < N) {
#pragma unroll
    for (int i = 0; i < 4; ++i)
      t[ty + 8 * i][tx] = in[(size_t)(k0 + ty + 8 * i) * N + n0 + tx];
    __syncthreads();
#pragma unroll
    for (int i = 0; i < 4; ++i)
      out[(size_t)(n0 + ty + 8 * i) * K + k0 + tx] = f2b(t[tx][ty + 8 * i]);
  } else {
#pragma unroll
    for (int i = 0; i < 4; ++i)
      out[(size_t)(n0 + ty + 8 * i) * K + k0 + tx] = 0;
  }
}

__global__ __launch_bounds__(256) void cvt_bf16(
    const float* __restrict__ in, ushortT* __restrict__ out) {
  int i = blockIdx.x * blockDim.x + threadIdx.x;
  float4 v = ((const float4*)in)[i];
  ushort4 o;
  o.x = f2b(v.x); o.y = f2b(v.y); o.z = f2b(v.z); o.w = f2b(v.w);
  ((ushort4*)out)[i] = o;
}

// ---- depthwise causal conv (bf16 in, bf16 out) -----------------------------
__global__ __launch_bounds__(256) void conv_kernel(
    const ushortT* __restrict__ xr, const float* __restrict__ w,
    const float* __restrict__ b, ushortT* __restrict__ u) {
  int idx = blockIdx.x * blockDim.x + threadIdx.x;
  int d = idx & (DI - 1);
  int s = (idx >> 10) & (S_LEN - 1);
  int bb = idx >> 20;
  const ushortT* xs = xr + (size_t)(bb * S_LEN) * (2 * DI) + d;
  float acc = b[d];
#pragma unroll
  for (int k = 0; k < 4; ++k) {
    int si = s - 3 + k;
    if (si >= 0) acc = fmaf(b2f(xs[(size_t)si * (2 * DI)]), w[d * 4 + k], acc);
  }
  u[idx] = f2b(acc);
}

// ---- split dbl[2048,288] -> dtin bf16[2048,32], Bb[2048,128], Cb[2048,128] --
__global__ __launch_bounds__(256) void cvt_bc(
    const float* __restrict__ dbl, ushortT* __restrict__ dtin,
    ushortT* __restrict__ Bb, ushortT* __restrict__ Cb) {
  int row = blockIdx.x, t = threadIdx.x;
  const float* base = dbl + (size_t)row * 288;
  {
    int col = t;
    float v = base[col];
    if (col < 32) dtin[(size_t)row * 32 + col] = f2b(v);
    else if (col < 160) Bb[(size_t)row * 128 + col - 32] = f2b(v);
    else Cb[(size_t)row * 128 + col - 160] = f2b(v);
  }
  if (t < 32) {
    int col = 256 + t;
    Cb[(size_t)row * 128 + col - 160] = f2b(base[col]);
  }
}

// ---- decay: per (b,c,d): D[t]=cumprod(1-dt) (fp32 out), ut[d][s]=bf16(u/D) --
__global__ __launch_bounds__(128) void decay_kernel(
    const float* __restrict__ dtb, const ushortT* __restrict__ u_bf,
    float* __restrict__ D, ushortT* __restrict__ ut) {
  __shared__ ushortT lt[128 * 66];
  int tid = threadIdx.x;
  int dg = blockIdx.x, bc = blockIdx.y;
  int b = bc >> 4, c = bc & 15;
  int d = dg * 128 + tid;
  size_t rb = ((size_t)(b * S_LEN + c * CL)) * DI + d;
  float cum = 1.f;
  for (int s = 0; s < CL; ++s) {
    float dt = dtb[rb + (size_t)s * DI];
    cum *= (1.f - dt);
    D[rb + (size_t)s * DI] = cum;
    float uu = b2f(u_bf[rb + (size_t)s * DI]);
    lt[tid * 66 + s] = f2b(uu / cum);
  }
  __syncthreads();
#pragma unroll
  for (int it = 0; it < 16; ++it) {
    int r = it * 8 + (tid >> 4);
    int s4 = (tid & 15) * 4;
    ushort4 o;
    o.x = lt[r * 66 + s4];
    o.y = lt[r * 66 + s4 + 1];
    o.z = lt[r * 66 + s4 + 2];
    o.w = lt[r * 66 + s4 + 3];
    *(ushort4*)&ut[(((size_t)bc * DI) + dg * 128 + r) * CL + s4] = o;
  }
}

// ---- Btr[b,c][n][s] = Bb[(bc*64+s)][n] -------------------------------------
__global__ __launch_bounds__(256) void btr_kernel(
    const ushortT* __restrict__ Bb, ushortT* __restrict__ btr) {
  int idx = blockIdx.x * blockDim.x + threadIdx.x;  // 32*128*64
  int s = idx & 63, n = (idx >> 6) & 127, bc = idx >> 13;
  btr[idx] = Bb[((size_t)bc * 64 + s) * 128 + n];
}

// ---- G[bc][t][s] = tril( C[t,:] . B[s,:] ), bf16 ---------------------------
__global__ __launch_bounds__(256) void gemm_g(
    const ushortT* __restrict__ Cb, const ushortT* __restrict__ Bb,
    ushortT* __restrict__ G) {
  int bc = blockIdx.x;
  int tid = threadIdx.x, l = tid & 63, w = tid >> 6;
  int row0 = bc * 64;
  f32x4 acc[4] = {};
#pragma unroll
  for (int kk = 0; kk < 4; ++kk) {
    short8 a = *(const short8*)&Cb[((size_t)row0 + w * 16 + (l & 15)) * 128 + kk * 32 + (l >> 4) * 8];
#pragma unroll
    for (int nf = 0; nf < 4; ++nf) {
      short8 bb = *(const short8*)&Bb[((size_t)row0 + nf * 16 + (l & 15)) * 128 + kk * 32 + (l >> 4) * 8];
      acc[nf] = __builtin_amdgcn_mfma_f32_16x16x32_bf16(a, bb, acc[nf], 0, 0, 0);
    }
  }
#pragma unroll
  for (int nf = 0; nf < 4; ++nf) {
    int s = nf * 16 + (l & 15);
#pragma unroll
    for (int i = 0; i < 4; ++i) {
      int t = w * 16 + (l >> 4) * 4 + i;
      float v = (s <= t) ? acc[nf][i] : 0.f;
      G[((size_t)bc * 64 + t) * 64 + s] = f2b(v);
    }
  }
}

// ---- Z[bc][d][n] = sum_s ut[d,s] * Btr[n,s]  (bf16 out into zb layout) ------
__global__ __launch_bounds__(256) void gemm_z(
    const ushortT* __restrict__ ut, const ushortT* __restrict__ btr,
    ushortT* __restrict__ zb) {
  __shared__ ushortT As[128 * 32];
  __shared__ ushortT Bs[128 * 32];
  const int tid = threadIdx.x;
  const int l = tid & 63, w = tid >> 6;
  const int wr = w >> 1, wc = w & 1;
  const int bc = blockIdx.z;
  const int b = bc >> 4, c = bc & 15;
  const int bm = blockIdx.y * 128;
  const ushortT* A = ut + (size_t)bc * DI * CL;
  const ushortT* Bt = btr + (size_t)bc * DS * CL;
  const int srow = l >> 2, scol = (l & 3) * 8;
  f32x4 acc[4][4] = {};
  for (int k0 = 0; k0 < CL; k0 += 32) {
#pragma unroll
    for (int j = 0; j < 2; ++j) {
      int sub = w * 2 + j;
      GLOAD16(A + (size_t)(bm + sub * 16 + srow) * CL + k0 + scol, &As[sub * 512]);
      GLOAD16(Bt + (size_t)(sub * 16 + srow) * CL + k0 + scol, &Bs[sub * 512]);
    }
    __syncthreads();
    short8 a[4], bb[4];
#pragma unroll
    for (int m = 0; m < 4; ++m)
      a[m] = *(const short8*)&As[(wr * 64 + m * 16 + (l & 15)) * 32 + (l >> 4) * 8];
#pragma unroll
    for (int n = 0; n < 4; ++n)
      bb[n] = *(const short8*)&Bs[(wc * 64 + n * 16 + (l & 15)) * 32 + (l >> 4) * 8];
#pragma unroll
    for (int m = 0; m < 4; ++m)
#pragma unroll
      for (int n = 0; n < 4; ++n)
        acc[m][n] = __builtin_amdgcn_mfma_f32_16x16x32_bf16(a[m], bb[n], acc[m][n], 0, 0, 0);
    __syncthreads();
  }
#pragma unroll
  for (int m = 0; m < 4; ++m) {
    int d = bm + wr * 64 + m * 16 + (l >> 4) * 4;
#pragma unroll
    for (int n = 0; n < 4; ++n) {
      int gn = wc * 64 + n * 16 + (l & 15);
#pragma unroll
      for (int i = 0; i < 4; ++i)
        zb[(((size_t)(b * DI + d + i)) * NC + c) * 128 + gn] = f2b(acc[m][n][i]);
    }
  }
}

// ---- pass2: h_entry chain over chunks; hstb bf16 = entry state --------------
__global__ __launch_bounds__(256) void scan_pass2(
    const ushortT* __restrict__ zb, const float* __restrict__ D,
    ushortT* __restrict__ hstb) {
  int wid = (blockIdx.x * blockDim.x + threadIdx.x) >> 6;  // 0..2047 = b*DI+d
  int lane = threadIdx.x & 63;
  int b = wid >> 10, d = wid & (DI - 1);
  size_t base = (size_t)wid * NC * 128;
  float h0 = 0.f, h1 = 0.f;
  for (int c = 0; c < NC; ++c) {
    float dend = D[((size_t)(b * S_LEN + c * CL + CL - 1)) * DI + d];
    ushort2 z2 = *(const ushort2*)&zb[base + c * 128 + 2 * lane];
    ushort2 he;
    he.x = f2b(h0); he.y = f2b(h1);
    *(ushort2*)&hstb[base + c * 128 + 2 * lane] = he;
    h0 = dend * (h0 + b2f(z2.x));
    h1 = dend * (h1 + b2f(z2.y));
  }
}

// ---- Y: yr[t,d] = bf16( D[t,d]*( G@ut + Cb@hstb ) + res ) -------------------
__global__ __launch_bounds__(256) void gemm_y(
    const ushortT* __restrict__ G, const ushortT* __restrict__ ut,
    const ushortT* __restrict__ Cb, const ushortT* __restrict__ hstb,
    const float* __restrict__ D, const ushortT* __restrict__ xr_bf,
    ushortT* __restrict__ yr) {
  const int tid = threadIdx.x;
  const int l = tid & 63, w = tid >> 6;
  const int bc = blockIdx.y, d0 = blockIdx.x * 256;
  const int b = bc >> 4, c = bc & 15;
  const int brow = b * S_LEN + c * CL;
  f32x4 acc[4][4] = {};
  // phase 1: K=64 (s): A = G rows, Bt = ut rows
#pragma unroll
  for (int kk = 0; kk < 2; ++kk) {
    short8 a[4], bb[4];
#pragma unroll
    for (int m = 0; m < 4; ++m)
      a[m] = *(const short8*)&G[((size_t)bc * 64 + m * 16 + (l & 15)) * 64 + kk * 32 + (l >> 4) * 8];
#pragma unroll
    for (int n = 0; n < 4; ++n) {
      int d = d0 + w * 64 + n * 16 + (l & 15);
      bb[n] = *(const short8*)&ut[((size_t)bc * DI + d) * CL + kk * 32 + (l >> 4) * 8];
    }
#pragma unroll
    for (int m = 0; m < 4; ++m)
#pragma unroll
      for (int n = 0; n < 4; ++n)
        acc[m][n] = __builtin_amdgcn_mfma_f32_16x16x32_bf16(a[m], bb[n], acc[m][n], 0, 0, 0);
  }
  // phase 2: K=128 (n): A = Cb rows, Bt = hstb rows
#pragma unroll
  for (int kk = 0; kk < 4; ++kk) {
    short8 a[4], bb[4];
#pragma unroll
    for (int m = 0; m < 4; ++m)
      a[m] = *(const short8*)&Cb[((size_t)brow + m * 16 + (l & 15)) * 128 + kk * 32 + (l >> 4) * 8];
#pragma unroll
    for (int n = 0; n < 4; ++n) {
      int d = d0 + w * 64 + n * 16 + (l & 15);
      bb[n] = *(const short8*)&hstb[((size_t)(b * DI + d)) * (NC * 128) + c * 128 + kk * 32 + (l >> 4) * 8];
    }
#pragma unroll
    for (int m = 0; m < 4; ++m)
#pragma unroll
      for (int n = 0; n < 4; ++n)
        acc[m][n] = __builtin_amdgcn_mfma_f32_16x16x32_bf16(a[m], bb[n], acc[m][n], 0, 0, 0);
  }
#pragma unroll
  for (int m = 0; m < 4; ++m) {
#pragma unroll
    for (int n = 0; n < 4; ++n) {
      int d = d0 + w * 64 + n * 16 + (l & 15);
#pragma unroll
      for (int i = 0; i < 4; ++i) {
        int gr = brow + m * 16 + (l >> 4) * 4 + i;
        float Dv = D[(size_t)gr * DI + d];
        float res = b2f(xr_bf[(size_t)gr * 2048 + 1024 + d]);
        yr[(size_t)gr * DI + d] = f2b(acc[m][n][i] * Dv + res);
      }
    }
  }
}

extern "C" void kernel_launch(void* const* d_in, const int* in_sizes, int n_in,
                              void* d_out, int out_size, void* d_ws, size_t ws_size,
                              hipStream_t stream) {
  const float* x      = (const float*)d_in[0];
  const float* W_in   = (const float*)d_in[1];
  const float* conv_w = (const float*)d_in[2];
  const float* conv_b = (const float*)d_in[3];
  const float* W_x    = (const float*)d_in[4];
  const float* W_dt   = (const float*)d_in[5];
  const float* b_dt   = (const float*)d_in[6];
  const float* W_out  = (const float*)d_in[7];
  float* out = (float*)d_out;
  float* ws = (float*)d_ws;

  // ---- workspace layout (float units), non-overlapping except noted aliases.
  // Lifetime-disjoint aliases: yr_bf<-dtb (dtb dead after decay, yr written
  // later); x_bf<-zb (x_bf dead after in-proj, zb written at step 9);
  // Wt_in<-hstb (Wt_in dead after in-proj, hstb written at step 10).
  // Total footprint: 14,139,392 floats = 56.6 MB.
  ushortT* xr_bf = (ushortT*)ws;                  // [2048,2048] bf16  (2,097,152 f)
  ushortT* u_bf  = (ushortT*)(ws + 2097152);      // [2048,1024] bf16  (1,048,576 f)
  float*   dbl   = ws + 3145728;                  // [2048,288] fp32   (589,824 f)
  float*   dtb   = ws + 3735552;                  // [2048,1024] fp32  (2,097,152 f)
  float*   Dc    = ws + 5832704;                  // [2048,1024] fp32  (2,097,152 f)
  ushortT* ut    = (ushortT*)(ws + 7929856);      // [32,1024,64] bf16 (1,048,576 f)
  ushortT* zb    = (ushortT*)(ws + 8978432);      // [2048,16,128] bf16(2,097,152 f)
  ushortT* hstb  = (ushortT*)(ws + 11075584);     // [2048,16,128] bf16(2,097,152 f)
  ushortT* Bb    = (ushortT*)(ws + 13172736);     // [2048,128] bf16   (131,072 f)
  ushortT* Cb    = (ushortT*)(ws + 13303808);     // [2048,128] bf16   (131,072 f)
  ushortT* btr   = (ushortT*)(ws + 13434880);     // [32,128,64] bf16  (131,072 f)
  ushortT* dtin  = (ushortT*)(ws + 13565952);     // [2048,32] bf16    (32,768 f)
  ushortT* G     = (ushortT*)(ws + 13598720);     // [32,64,64] bf16   (65,536 f)
  ushortT* Wt_x  = (ushortT*)(ws + 13664256);     // [384,1024] bf16   (196,608 f)
  ushortT* Wt_out= (ushortT*)(ws + 13860864);     // [512,1024] bf16   (262,144 f)
  ushortT* Wt_dt = (ushortT*)(ws + 14123008);     // [1024,32] bf16    (16,384 f)
  ushortT* yr_bf = (ushortT*)dtb;                 // alias: [2048,1024] bf16
  ushortT* x_bf  = (ushortT*)zb;                  // alias: [2048,512] bf16
  ushortT* Wt_in = (ushortT*)hstb;                // alias: [2048,512] bf16

  dim3 blk(256);
  dim3 tblk(32, 8);
  transpose_cvt<<<dim3(64, 16), tblk, 0, stream>>>(W_in, Wt_in, DM, 2 * DI);
  transpose_cvt<<<dim3(12, 32), tblk, 0, stream>>>(W_x, Wt_x, DI, DTR + 2 * DS);
  transpose_cvt<<<dim3(16, 32), tblk, 0, stream>>>(W_out, Wt_out, DI, DM);
  transpose_cvt<<<dim3(32, 1), tblk, 0, stream>>>(W_dt, Wt_dt, DTR, DI);
  cvt_bf16<<<1024, blk, 0, stream>>>(x, x_bf);
  // 1) in-proj: xr = x @ W_in (bf16)  M=2048 N=2048 K=512
  gemm_mfma<1><<<dim3(16, 16), blk, 0, stream>>>(x_bf, Wt_in, nullptr, xr_bf, 2 * DI, DM, 2 * DI);
  // 2) conv -> u (bf16)
  conv_kernel<<<(BATCH * S_LEN * DI) / 256, blk, 0, stream>>>(xr_bf, conv_w, conv_b, u_bf);
  // 3) x-proj: dbl = u @ W_x (fp32)   M=2048 N=288 K=1024
  gemm_mfma<0><<<dim3(3, 16), blk, 0, stream>>>(u_bf, Wt_x, nullptr, dbl, DTR + 2 * DS, DI, DTR + 2 * DS);
  // 4) split dbl -> dtin/Bb/Cb (bf16)
  cvt_bc<<<2048, blk, 0, stream>>>(dbl, dtin, Bb, Cb);
  // 5) dt-proj (MFMA + softplus/clip epi): dtb = f(dtin @ W_dt + b_dt)
  gemm_mfma<2><<<dim3(8, 16), blk, 0, stream>>>(dtin, Wt_dt, b_dt, dtb, DI, DTR, DI);
  // 6) decay cumprod D + ut = bf16(u/D)
  decay_kernel<<<dim3(8, 32), dim3(128), 0, stream>>>(dtb, u_bf, Dc, ut);
  // 7) Btr per chunk
  btr_kernel<<<1024, blk, 0, stream>>>(Bb, btr);
  // 8) G = tril(C B^T) per chunk
  gemm_g<<<32, blk, 0, stream>>>(Cb, Bb, G);
  // 9) Z = ut @ Btr^T per chunk -> zb
  gemm_z<<<dim3(1, 8, 32), blk, 0, stream>>>(ut, btr, zb);
  // 10) chunk-boundary combine -> hstb (entry states, bf16)
  scan_pass2<<<512, blk, 0, stream>>>(zb, Dc, hstb);
  // 11) Y = D*(G@ut + C@h_entry) + res -> yr_bf
  gemm_y<<<dim3(4, 32), blk, 0, stream>>>(G, ut, Cb, hstb, Dc, xr_bf, yr_bf);
  // 12) out-proj: out = yr @ W_out (fp32)  M=2048 N=512 K=1024
  gemm_mfma<0><<<dim3(4, 16), blk, 0, stream>>>(yr_bf, Wt_out, nullptr, out, DM, DI, DM);
}